// Round 11
// baseline (142.134 us; speedup 1.0000x reference)
//
#include <hip/hip_runtime.h>

#define BB 2048          // batches
#define TT 4096          // timesteps
#define LN2 0.69314718055994530942f

// ---------------------------------------------------------------------------
// One-kernel CRF (round 11): single-generation + DPP fold + fused reduction.
// Session laws applied:
//   * HARD 64-VGPR budget (R2/4/5/6/7): live-set must fit 64.
//   * Single generation needs 16 steps/thread (8192 waves): done as TWO
//     8-step halves through ONE reused Lf[24] (R5 failed by holding both).
//   * Barrier coupling kills (R10): exactly one mid-kernel __syncthreads.
//   * DPP fold, not shfl/DS (R9, +3.6us): lane63 result, verified ladder.
//   * Fold renorms only at rounds 3/6 (power-of-2 scaling is exact; growth
//     <= 3^3 per span, fp32-safe).
//   * Transition counts: 3-bit x9 per half (<=7 each); cross-half seam added
//     directly once. Unpack dots use trans[p] (constant idx -> s_load).
//   * Fused final reduction: last block (atomic counter, memset at launch)
//     sums the 2048 nll in crf_reduce's exact order. One launch saved.
// Grid: 2048 blocks x 256 thr = 8 blocks/CU = ALL resident, one generation.
// ---------------------------------------------------------------------------
template<int CTRL>
__device__ __forceinline__ float dppf(float x) {
    return __int_as_float(__builtin_amdgcn_update_dpp(
        0, __float_as_int(x), CTRL, 0xF, 0xF, true));
}
template<int CTRL>
__device__ __forceinline__ int dppi(int x) {
    return __builtin_amdgcn_update_dpp(0, x, CTRL, 0xF, 0xF, true);
}

__global__ __launch_bounds__(256) void crf_pass1(
    const float* __restrict__ logits, const float* __restrict__ trans,
    const int* __restrict__ tags, float* __restrict__ ws,
    float* __restrict__ out, unsigned* __restrict__ counter)
{
    __shared__ float sTrans[9];
    __shared__ float sTrExp[9];
    __shared__ float sRec[3][12];      // records of waves 0..2
    __shared__ float sV[3];            // alpha0 from chunk-0 thread
    __shared__ float sPart[4];
    __shared__ int   sLast;

    const int tid = threadIdx.x;
    if (tid < 9) {
        float tv = trans[tid];
        sTrans[tid] = tv;
        sTrExp[tid] = __expf(tv);
    }
    __syncthreads();

    const int b    = blockIdx.x;
    const int c    = tid;              // chunk: steps [16c, 16c+16)
    const int lane = tid & 63;
    const int wid  = tid >> 6;

    const int4*   tp = (const int4*)(tags + (size_t)b * TT + (size_t)c * 16);
    const float4* lp = (const float4*)(logits + ((size_t)b * TT + (size_t)c * 16) * 3);

    // ---- half-1 clause: tags first, then logits ----
    int4 T0 = tp[0], T1 = tp[1];
    float Lf[24];
#pragma unroll
    for (int i = 0; i < 6; ++i) {
        float4 t = lp[i];
        Lf[4*i+0] = t.x; Lf[4*i+1] = t.y; Lf[4*i+2] = t.z; Lf[4*i+3] = t.w;
    }
    __builtin_amdgcn_sched_barrier(0);

#define PACK8(A_, B_) ( (unsigned)(A_).x        | ((unsigned)(A_).y << 2)  \
                      | ((unsigned)(A_).z << 4)  | ((unsigned)(A_).w << 6)  \
                      | ((unsigned)(B_).x << 8)  | ((unsigned)(B_).y << 10) \
                      | ((unsigned)(B_).z << 12) | ((unsigned)(B_).w << 14) )

    const unsigned pk1 = PACK8(T0, T1);   // waits tags only; logits stream on

    const float t00 = sTrExp[0], t01 = sTrExp[1], t02 = sTrExp[2];
    const float t10 = sTrExp[3], t11 = sTrExp[4], t12 = sTrExp[5];
    const float t20 = sTrExp[6], t21 = sTrExp[7], t22 = sTrExp[8];

    float a00 = 1.f, a01 = 0.f, a02 = 0.f;
    float a10 = 0.f, a11 = 1.f, a12 = 0.f;
    float a20 = 0.f, a21 = 0.f, a22 = 1.f;
    int   se = 0;
    float score = 0.f;
    unsigned acc = 0u;                 // 9 x 3-bit counters (<=7 per half)
    int prev = 0;

#define MATSTEP(e0_, e1_, e2_) do {                                     \
    float x0 = __expf(e0_), x1 = __expf(e1_), x2 = __expf(e2_);         \
    float b0_ = (a00*t00 + a01*t10 + a02*t20) * x0;                     \
    float b1_ = (a00*t01 + a01*t11 + a02*t21) * x1;                     \
    float b2_ = (a00*t02 + a01*t12 + a02*t22) * x2;                     \
    float b3_ = (a10*t00 + a11*t10 + a12*t20) * x0;                     \
    float b4_ = (a10*t01 + a11*t11 + a12*t21) * x1;                     \
    float b5_ = (a10*t02 + a11*t12 + a12*t22) * x2;                     \
    float b6_ = (a20*t00 + a21*t10 + a22*t20) * x0;                     \
    float b7_ = (a20*t01 + a21*t11 + a22*t21) * x1;                     \
    float b8_ = (a20*t02 + a21*t12 + a22*t22) * x2;                     \
    a00=b0_; a01=b1_; a02=b2_; a10=b3_; a11=b4_; a12=b5_; a20=b6_; a21=b7_; a22=b8_; \
} while (0)

#define RENORM do {                                                     \
    float m_ = fmaxf(fmaxf(fmaxf(a00, a01), fmaxf(a02, a10)),           \
                     fmaxf(fmaxf(a11, a12), fmaxf(fmaxf(a20, a21), a22))); \
    int ef_ = (int)(__float_as_uint(m_) >> 23);                         \
    float scf_ = __uint_as_float((unsigned)(254 - ef_) << 23);          \
    se += ef_ - 127;                                                    \
    a00 *= scf_; a01 *= scf_; a02 *= scf_;                              \
    a10 *= scf_; a11 *= scf_; a12 *= scf_;                              \
    a20 *= scf_; a21 *= scf_; a22 *= scf_;                              \
} while (0)

    // ---- steps 0..7 (half 1) ----
#pragma unroll
    for (int s = 0; s < 8; ++s) {
        float e0 = Lf[3*s+0], e1 = Lf[3*s+1], e2 = Lf[3*s+2];
        int tg = (int)((pk1 >> (2*s)) & 3u);
        if (s == 0) {
            if (c == 0) {              // t=0: alpha0 -> LDS immediately
                sV[0] = __expf(e0); sV[1] = __expf(e1); sV[2] = __expf(e2);
            } else {
                MATSTEP(e0, e1, e2);
            }
        } else {
            MATSTEP(e0, e1, e2);
            acc += 1u << (3 * (prev * 3 + tg));
        }
        score += (tg == 0) ? e0 : ((tg == 1) ? e1 : e2);
        prev = tg;
    }
    RENORM;
#pragma unroll
    for (int p = 0; p < 9; ++p)        // constant idx -> scalar loads
        score += (float)((int)((acc >> (3 * p)) & 7u)) * trans[p];
    acc = 0u;

    // ---- half-2 clause into the SAME regs (WAR-ordered after last use) ----
    T0 = tp[2]; T1 = tp[3];
#pragma unroll
    for (int i = 0; i < 6; ++i) {
        float4 t = lp[6 + i];
        Lf[4*i+0] = t.x; Lf[4*i+1] = t.y; Lf[4*i+2] = t.z; Lf[4*i+3] = t.w;
    }
    __builtin_amdgcn_sched_barrier(0);

    const unsigned pk2 = PACK8(T0, T1);

    // ---- steps 8..15 (half 2) ----
#pragma unroll
    for (int s = 0; s < 8; ++s) {
        float e0 = Lf[3*s+0], e1 = Lf[3*s+1], e2 = Lf[3*s+2];
        int tg = (int)((pk2 >> (2*s)) & 3u);
        MATSTEP(e0, e1, e2);
        if (s == 0) score += sTrans[prev * 3 + tg];   // cross-half seam (keeps acc <=7)
        else        acc += 1u << (3 * (prev * 3 + tg));
        score += (tg == 0) ? e0 : ((tg == 1) ? e1 : e2);
        prev = tg;
    }
    RENORM;
#pragma unroll
    for (int p = 0; p < 9; ++p)
        score += (float)((int)((acc >> (3 * p)) & 7u)) * trans[p];

    // ---- in-wave seam: chunk c-1 -> c (lane 0 handled as wave-seam) ----
    {
        int opv = __shfl_up(prev, 1, 64);
        if (lane != 0) score += sTrans[opv * 3 + (int)(pk1 & 3u)];
    }
    int fp = (int)(pk1 & 3u) | (prev << 8);   // firstTag | lastTag<<8

    // ---- DPP ordered fold (lane 63 result); renorm rounds 3 & 6 only ----
#define FOLD_ROUND(CTRL, RN) do {                                       \
    float o00=dppf<CTRL>(a00), o01=dppf<CTRL>(a01), o02=dppf<CTRL>(a02);\
    float o10=dppf<CTRL>(a10), o11=dppf<CTRL>(a11), o12=dppf<CTRL>(a12);\
    float o20=dppf<CTRL>(a20), o21=dppf<CTRL>(a21), o22=dppf<CTRL>(a22);\
    int   ose=dppi<CTRL>(se);                                           \
    float osc=dppf<CTRL>(score);                                        \
    int   ofp=dppi<CTRL>(fp);                                           \
    float c00=o00*a00+o01*a10+o02*a20;                                  \
    float c01=o00*a01+o01*a11+o02*a21;                                  \
    float c02=o00*a02+o01*a12+o02*a22;                                  \
    float c10=o10*a00+o11*a10+o12*a20;                                  \
    float c11=o10*a01+o11*a11+o12*a21;                                  \
    float c12=o10*a02+o11*a12+o12*a22;                                  \
    float c20=o20*a00+o21*a10+o22*a20;                                  \
    float c21=o20*a01+o21*a11+o22*a21;                                  \
    float c22=o20*a02+o21*a12+o22*a22;                                  \
    score += osc; se += ose;                                            \
    fp = (ofp & 255) | (fp & 0xFF00);                                   \
    a00=c00; a01=c01; a02=c02; a10=c10; a11=c11; a12=c12;               \
    a20=c20; a21=c21; a22=c22;                                          \
    if (RN) RENORM;                                                     \
} while (0)

    FOLD_ROUND(0x111, false);   // row_shr:1
    FOLD_ROUND(0x112, false);   // row_shr:2
    FOLD_ROUND(0x114, true);    // row_shr:4   (renorm: growth <= 3^3)
    FOLD_ROUND(0x118, false);   // row_shr:8
    FOLD_ROUND(0x142, false);   // row_bcast:15
    FOLD_ROUND(0x143, true);    // row_bcast:31 (renorm -> sRec in [0.5,1))

    // ---- cross-wave fold (4 waves, time-ordered); combiner = tid 255 ----
    if (lane == 63 && wid < 3) {
        sRec[wid][0] = a00; sRec[wid][1] = a01; sRec[wid][2] = a02;
        sRec[wid][3] = a10; sRec[wid][4] = a11; sRec[wid][5] = a12;
        sRec[wid][6] = a20; sRec[wid][7] = a21; sRec[wid][8] = a22;
        sRec[wid][9]  = __int_as_float(se);
        sRec[wid][10] = score;
        sRec[wid][11] = __int_as_float(fp);
    }
    __syncthreads();

    if (tid == 255) {                  // wave 3 lane 63: holds last product
        float p00 = sRec[0][0], p01 = sRec[0][1], p02 = sRec[0][2];
        float p10 = sRec[0][3], p11 = sRec[0][4], p12 = sRec[0][5];
        float p20 = sRec[0][6], p21 = sRec[0][7], p22 = sRec[0][8];
        int   seT   = __float_as_int(sRec[0][9]);
        float scT   = sRec[0][10];
        int   lastT = __float_as_int(sRec[0][11]) >> 8;

#pragma unroll
        for (int k = 1; k < 3; ++k) {
            float m00 = sRec[k][0], m01 = sRec[k][1], m02 = sRec[k][2];
            float m10 = sRec[k][3], m11 = sRec[k][4], m12 = sRec[k][5];
            float m20 = sRec[k][6], m21 = sRec[k][7], m22 = sRec[k][8];
            int   shm = __float_as_int(sRec[k][9]);
            float scm = sRec[k][10];
            int   pkm = __float_as_int(sRec[k][11]);

            float c00 = p00*m00 + p01*m10 + p02*m20;
            float c01 = p00*m01 + p01*m11 + p02*m21;
            float c02 = p00*m02 + p01*m12 + p02*m22;
            float c10 = p10*m00 + p11*m10 + p12*m20;
            float c11 = p10*m01 + p11*m11 + p12*m21;
            float c12 = p10*m02 + p11*m12 + p12*m22;
            float c20 = p20*m00 + p21*m10 + p22*m20;
            float c21 = p20*m01 + p21*m11 + p22*m21;
            float c22 = p20*m02 + p21*m12 + p22*m22;

            scT += scm + sTrans[lastT * 3 + (pkm & 255)];
            lastT = pkm >> 8;
            seT  += shm;
            p00=c00; p01=c01; p02=c02; p10=c10; p11=c11; p12=c12;
            p20=c20; p21=c21; p22=c22;
        }
        {   // fold own (wave 3) record; max growth 3^3 -> no renorm needed
            float c00 = p00*a00 + p01*a10 + p02*a20;
            float c01 = p00*a01 + p01*a11 + p02*a21;
            float c02 = p00*a02 + p01*a12 + p02*a22;
            float c10 = p10*a00 + p11*a10 + p12*a20;
            float c11 = p10*a01 + p11*a11 + p12*a21;
            float c12 = p10*a02 + p11*a12 + p12*a22;
            float c20 = p20*a00 + p21*a10 + p22*a20;
            float c21 = p20*a01 + p21*a11 + p22*a21;
            float c22 = p20*a02 + p21*a12 + p22*a22;

            scT += score + sTrans[lastT * 3 + (fp & 255)];
            seT += se;
            p00=c00; p01=c01; p02=c02; p10=c10; p11=c11; p12=c12;
            p20=c20; p21=c21; p22=c22;
        }
        float w0 = sV[0], w1 = sV[1], w2 = sV[2];
        float n0 = w0*p00 + w1*p10 + w2*p20;
        float n1 = w0*p01 + w1*p11 + w2*p21;
        float n2 = w0*p02 + w1*p12 + w2*p22;
        float logz = logf(n0 + n1 + n2) + (float)seT * LN2;
        ws[b] = logz - scT;            // per-batch nll
        __threadfence();               // device-scope release of ws[b]
    }
    __syncthreads();

    // ---- fused reduction: last-arriving block sums all 2048 nll ----
    if (tid == 0) {
        unsigned old = atomicAdd(counter, 1u);
        sLast = (old == (unsigned)(gridDim.x - 1));
        __threadfence();               // acquire side
    }
    __syncthreads();
    if (sLast) {                       // block-uniform
        float s = 0.f;
#pragma unroll
        for (int k = 0; k < BB / 256; ++k) s += ws[k * 256 + tid];
        for (int off = 32; off > 0; off >>= 1) s += __shfl_down(s, off, 64);
        if (lane == 0) sPart[wid] = s;
        __syncthreads();
        if (tid == 0) out[0] = sPart[0] + sPart[1] + sPart[2] + sPart[3];
    }

#undef MATSTEP
#undef RENORM
#undef FOLD_ROUND
#undef PACK8
}

extern "C" void kernel_launch(void* const* d_in, const int* in_sizes, int n_in,
                              void* d_out, int out_size, void* d_ws, size_t ws_size,
                              hipStream_t stream) {
    const float* logits = (const float*)d_in[0];
    const float* trans  = (const float*)d_in[1];
    const int*   tags   = (const int*)d_in[2];
    float* out = (float*)d_out;
    float* ws  = (float*)d_ws;
    unsigned* counter = (unsigned*)((char*)d_ws + (size_t)BB * 4);

    hipMemsetAsync(counter, 0, 4, stream);   // ws is harness-poisoned, not zero
    crf_pass1<<<dim3(BB), dim3(256), 0, stream>>>(logits, trans, tags, ws, out, counter);
}